// Round 2
// baseline (460.926 us; speedup 1.0000x reference)
//
#include <hip/hip_runtime.h>

// Problem: x (32,4,512,512) fp32.
// reference = InstanceNorm( sum_j (2^j/15) * ((x * k_j + 1) * 0.5) )
// Collapses to: c = x * K (single 3x3 depthwise, zero pad, K entries sum to 0,
// center weight 1), then (c - mean_c) * rsqrt(var_c + 4e-5)
// [affine 0.5c+0.5 cancels in InstanceNorm; eps 1e-5 scales by 1/0.25]
//
// Two kernels (R1 post-mortem: co-resident fused+spin capped occupancy at 43%
// and regressed; two launches with a full wave pool win).
//   2048 blocks x 256 thr (4 waves), 8 blocks/CU -> 32 waves/CU.
//   Wave = full 512-col x 8-row strip: lane i holds cols [4i,4i+4) (seg A)
//   and [256+4i,..) (seg B). ALL halos via shfl (plane edges zero-pad):
//   exactly 2 coalesced dwordx4 per row per wave, zero divergent loads.
//   Pass 1: conv-on-the-fly (s,ss) partials -> ws.
//   Pass 2: reduce plane's 16 partials, recompute conv (x is L3-resident:
//   R1 measured FETCH == 1x size of x), normalize, NT store.

#define H 512
#define W 512
#define PLANES 128
#define NBLOCKS (PLANES * 16)   // 16 blocks/plane, 32 rows/block, 8 rows/wave

typedef float vfloat4 __attribute__((ext_vector_type(4)));

// combined kernel weights (x 1/30): [-8 -4 -2; -1 30 -1; -2 -4 -8]
#define WT0 (-8.0f/30.0f)
#define WT1 (-4.0f/30.0f)
#define WT2 (-2.0f/30.0f)
#define WM  (-1.0f/30.0f)

// Load one full 512-col row for a wave: 2 float4 per lane + shfl halos.
// `valid` is wave-uniform (row in bounds).
__device__ __forceinline__ void wload2(const float* __restrict__ rowp, int lane, bool valid,
                                       float& lA, float4& mA, float& rA,
                                       float& lB, float4& mB, float& rB) {
    if (valid) {
        mA = *reinterpret_cast<const float4*>(rowp + lane * 4);
        mB = *reinterpret_cast<const float4*>(rowp + 256 + lane * 4);
    } else {
        mA = make_float4(0.0f, 0.0f, 0.0f, 0.0f);
        mB = make_float4(0.0f, 0.0f, 0.0f, 0.0f);
    }
    float upA = __shfl_up(mA.w, 1);
    float dnA = __shfl_down(mA.x, 1);
    float upB = __shfl_up(mB.w, 1);
    float dnB = __shfl_down(mB.x, 1);
    float c255 = __shfl(mA.w, 63);   // col 255 -> seg B lane 0 left halo
    float c256 = __shfl(mB.x, 0);    // col 256 -> seg A lane 63 right halo
    lA = (lane == 0)  ? 0.0f : upA;  // col -1 is zero pad
    rA = (lane == 63) ? c256 : dnA;
    lB = (lane == 0)  ? c255 : upB;
    rB = (lane == 63) ? 0.0f : dnB;  // col 512 is zero pad
}

// 180-degree-symmetric kernel -> pair taps: 4 FMA + 4 ADD per output.
__device__ __forceinline__ float4 conv_row(float al, float4 a, float ar,
                                           float bl, float4 b, float br,
                                           float dl, float4 d, float dr) {
    float4 o;
    o.x = b.x + WT0*(al  + d.y) + WT1*(a.x + d.x) + WT2*(a.y + dl ) + WM*(bl  + b.y);
    o.y = b.y + WT0*(a.x + d.z) + WT1*(a.y + d.y) + WT2*(a.z + d.x) + WM*(b.x + b.z);
    o.z = b.z + WT0*(a.y + d.w) + WT1*(a.z + d.z) + WT2*(a.w + d.y) + WM*(b.y + b.w);
    o.w = b.w + WT0*(a.z + dr ) + WT1*(a.w + d.w) + WT2*(ar  + d.z) + WM*(b.z + br );
    return o;
}

// Pass 1: conv on the fly, per-block (sum, sumsq) partial.
__global__ __launch_bounds__(256, 8) void stats_kernel(const float* __restrict__ x,
                                                       float* __restrict__ ws) {
    const int tid   = threadIdx.x;
    const int wid   = tid >> 6;
    const int lane  = tid & 63;
    const int plane = blockIdx.x >> 4;
    const int slab  = blockIdx.x & 15;         // 32-row slab
    const int r0    = slab * 32 + wid * 8;     // 8-row wave strip

    const float* __restrict__ p = x + (size_t)plane * H * W;

    float alA, arA, blA, brA, dlA, drA;
    float alB, arB, blB, brB, dlB, drB;
    float4 aA, bA, dA, aB, bB, dB;

    wload2(p + (size_t)(r0 - 1) * W, lane, r0 > 0, alA, aA, arA, alB, aB, arB);
    wload2(p + (size_t)r0 * W,       lane, true,   blA, bA, brA, blB, bB, brB);

    float s = 0.0f, ss = 0.0f;
    #pragma unroll
    for (int r = r0; r < r0 + 8; ++r) {
        wload2(p + (size_t)(r + 1) * W, lane, (r + 1) < H, dlA, dA, drA, dlB, dB, drB);
        float4 oA = conv_row(alA, aA, arA, blA, bA, brA, dlA, dA, drA);
        float4 oB = conv_row(alB, aB, arB, blB, bB, brB, dlB, dB, drB);
        s  += ((oA.x + oA.y) + (oA.z + oA.w)) + ((oB.x + oB.y) + (oB.z + oB.w));
        ss += ((oA.x*oA.x + oA.y*oA.y) + (oA.z*oA.z + oA.w*oA.w))
            + ((oB.x*oB.x + oB.y*oB.y) + (oB.z*oB.z + oB.w*oB.w));
        alA = blA; aA = bA; arA = brA;  alB = blB; aB = bB; arB = brB;
        blA = dlA; bA = dA; brA = drA;  blB = dlB; bB = dB; brB = drB;
    }

    for (int off = 32; off > 0; off >>= 1) {
        s  += __shfl_down(s,  off);
        ss += __shfl_down(ss, off);
    }
    __shared__ float sh[8];
    if (lane == 0) { sh[wid * 2] = s; sh[wid * 2 + 1] = ss; }
    __syncthreads();
    if (tid == 0) {
        ws[blockIdx.x * 2 + 0] = (sh[0] + sh[2]) + (sh[4] + sh[6]);
        ws[blockIdx.x * 2 + 1] = (sh[1] + sh[3]) + (sh[5] + sh[7]);
    }
}

// Pass 2: reduce the plane's 16 partials, recompute conv (x is L3-resident),
// normalize, nontemporal-store.
__global__ __launch_bounds__(256, 8) void norm_kernel(const float* __restrict__ x,
                                                      const float* __restrict__ ws,
                                                      float* __restrict__ out) {
    const int tid   = threadIdx.x;
    const int wid   = tid >> 6;
    const int lane  = tid & 63;
    const int plane = blockIdx.x >> 4;
    const int slab  = blockIdx.x & 15;
    const int r0    = slab * 32 + wid * 8;
    const int c0A   = lane * 4;
    const int c0B   = 256 + lane * 4;

    const float* __restrict__ p = x + (size_t)plane * H * W;

    // Prefetch the first two rows BEFORE touching the partials: the row loads
    // are independent of the stats, so their L3 latency hides under the
    // partial-read + reduce + syncthreads.
    float alA, arA, blA, brA, dlA, drA;
    float alB, arB, blB, brB, dlB, drB;
    float4 aA, bA, dA, aB, bB, dB;
    wload2(p + (size_t)(r0 - 1) * W, lane, r0 > 0, alA, aA, arA, alB, aB, arB);
    wload2(p + (size_t)r0 * W,       lane, true,   blA, bA, brA, blB, bB, brB);

    // plane stats: 16 (s,ss) pairs; wave 0 reduces, LDS-broadcasts.
    __shared__ float sb[2];
    if (tid < 64) {
        float s = 0.0f, ss = 0.0f;
        if (lane < 16) {
            s  = ws[(plane * 16 + lane) * 2 + 0];
            ss = ws[(plane * 16 + lane) * 2 + 1];
        }
        for (int off = 8; off > 0; off >>= 1) {
            s  += __shfl_down(s,  off);
            ss += __shfl_down(ss, off);
        }
        if (lane == 0) { sb[0] = s; sb[1] = ss; }
    }
    __syncthreads();
    const float invN = 1.0f / (float)(H * W);
    const float mean = sb[0] * invN;
    const float var  = sb[1] * invN - mean * mean;
    const float rstd = rsqrtf(var + 4e-5f);

    float* __restrict__ q = out + (size_t)plane * H * W;

    #pragma unroll
    for (int r = r0; r < r0 + 8; ++r) {
        wload2(p + (size_t)(r + 1) * W, lane, (r + 1) < H, dlA, dA, drA, dlB, dB, drB);
        float4 oA = conv_row(alA, aA, arA, blA, bA, brA, dlA, dA, drA);
        float4 oB = conv_row(alB, aB, arB, blB, bB, brB, dlB, dB, drB);
        vfloat4 yA, yB;
        yA.x = (oA.x - mean) * rstd;
        yA.y = (oA.y - mean) * rstd;
        yA.z = (oA.z - mean) * rstd;
        yA.w = (oA.w - mean) * rstd;
        yB.x = (oB.x - mean) * rstd;
        yB.y = (oB.y - mean) * rstd;
        yB.z = (oB.z - mean) * rstd;
        yB.w = (oB.w - mean) * rstd;
        __builtin_nontemporal_store(yA, reinterpret_cast<vfloat4*>(q + (size_t)r * W + c0A));
        __builtin_nontemporal_store(yB, reinterpret_cast<vfloat4*>(q + (size_t)r * W + c0B));
        alA = blA; aA = bA; arA = brA;  alB = blB; aB = bB; arB = brB;
        blA = dlA; bA = dA; brA = drA;  blB = dlB; bB = dB; brB = drB;
    }
}

extern "C" void kernel_launch(void* const* d_in, const int* in_sizes, int n_in,
                              void* d_out, int out_size, void* d_ws, size_t ws_size,
                              hipStream_t stream) {
    const float* x = (const float*)d_in[0];
    float* out = (float*)d_out;
    float* ws  = (float*)d_ws;

    stats_kernel<<<dim3(NBLOCKS), dim3(256), 0, stream>>>(x, ws);
    norm_kernel <<<dim3(NBLOCKS), dim3(256), 0, stream>>>(x, ws, out);
}

// Round 3
// 262.141 us; speedup vs baseline: 1.7583x; 1.7583x over previous
//
#include <hip/hip_runtime.h>

// Problem: x (32,4,512,512) fp32.
// reference = InstanceNorm( sum_j (2^j/15) * ((x * k_j + 1) * 0.5) )
// Collapses to: c = x * K (single 3x3 depthwise, zero pad, K entries sum to 0,
// center weight 1), then (c - mean_c) * rsqrt(var_c + 4e-5)
// [affine 0.5c+0.5 cancels in InstanceNorm; eps 1e-5 scales by 1/0.25]
//
// Two kernels (R1: fused+spin capped occupancy at 43%, regressed).
//   2048 blocks x 256 thr (4 waves), 8 blocks/CU -> 32 waves/CU.
//   Wave = full 512-col x 8-row strip: lane i holds cols [4i,4i+4) (seg A)
//   and [256+4i,..) (seg B). ALL halos via shfl (plane edges zero-pad):
//   exactly 2 coalesced dwordx4 per row per wave, zero divergent loads.
//   Pass 1: conv-on-the-fly (s,ss) partials -> ws.
//   Pass 2: reduce plane's 16 partials, recompute conv (x is L3-resident:
//   R1 measured FETCH == 1x size of x), normalize, NT store.
//
// R2 post-mortem: __launch_bounds__(256,8) over-squeezed the allocator to
// 32 VGPR and spilled the row buffers to scratch (WRITE_SIZE 370 MB on a
// 16 KB-writing kernel; 182 us). (256,4) keeps the ~40-VGPR natural
// allocation -> no spill, still 8 waves/EU achievable.

#define H 512
#define W 512
#define PLANES 128
#define NBLOCKS (PLANES * 16)   // 16 blocks/plane, 32 rows/block, 8 rows/wave

typedef float vfloat4 __attribute__((ext_vector_type(4)));

// combined kernel weights (x 1/30): [-8 -4 -2; -1 30 -1; -2 -4 -8]
#define WT0 (-8.0f/30.0f)
#define WT1 (-4.0f/30.0f)
#define WT2 (-2.0f/30.0f)
#define WM  (-1.0f/30.0f)

// Load one full 512-col row for a wave: 2 float4 per lane + shfl halos.
// `valid` is wave-uniform (row in bounds).
__device__ __forceinline__ void wload2(const float* __restrict__ rowp, int lane, bool valid,
                                       float& lA, float4& mA, float& rA,
                                       float& lB, float4& mB, float& rB) {
    if (valid) {
        mA = *reinterpret_cast<const float4*>(rowp + lane * 4);
        mB = *reinterpret_cast<const float4*>(rowp + 256 + lane * 4);
    } else {
        mA = make_float4(0.0f, 0.0f, 0.0f, 0.0f);
        mB = make_float4(0.0f, 0.0f, 0.0f, 0.0f);
    }
    float upA = __shfl_up(mA.w, 1);
    float dnA = __shfl_down(mA.x, 1);
    float upB = __shfl_up(mB.w, 1);
    float dnB = __shfl_down(mB.x, 1);
    float c255 = __shfl(mA.w, 63);   // col 255 -> seg B lane 0 left halo
    float c256 = __shfl(mB.x, 0);    // col 256 -> seg A lane 63 right halo
    lA = (lane == 0)  ? 0.0f : upA;  // col -1 is zero pad
    rA = (lane == 63) ? c256 : dnA;
    lB = (lane == 0)  ? c255 : upB;
    rB = (lane == 63) ? 0.0f : dnB;  // col 512 is zero pad
}

// 180-degree-symmetric kernel -> pair taps: 4 FMA + 4 ADD per output.
__device__ __forceinline__ float4 conv_row(float al, float4 a, float ar,
                                           float bl, float4 b, float br,
                                           float dl, float4 d, float dr) {
    float4 o;
    o.x = b.x + WT0*(al  + d.y) + WT1*(a.x + d.x) + WT2*(a.y + dl ) + WM*(bl  + b.y);
    o.y = b.y + WT0*(a.x + d.z) + WT1*(a.y + d.y) + WT2*(a.z + d.x) + WM*(b.x + b.z);
    o.z = b.z + WT0*(a.y + d.w) + WT1*(a.z + d.z) + WT2*(a.w + d.y) + WM*(b.y + b.w);
    o.w = b.w + WT0*(a.z + dr ) + WT1*(a.w + d.w) + WT2*(ar  + d.z) + WM*(b.z + br );
    return o;
}

// Pass 1: conv on the fly, per-block (sum, sumsq) partial.
__global__ __launch_bounds__(256, 4) void stats_kernel(const float* __restrict__ x,
                                                       float* __restrict__ ws) {
    const int tid   = threadIdx.x;
    const int wid   = tid >> 6;
    const int lane  = tid & 63;
    const int plane = blockIdx.x >> 4;
    const int slab  = blockIdx.x & 15;         // 32-row slab
    const int r0    = slab * 32 + wid * 8;     // 8-row wave strip

    const float* __restrict__ p = x + (size_t)plane * H * W;

    float alA, arA, blA, brA, dlA, drA;
    float alB, arB, blB, brB, dlB, drB;
    float4 aA, bA, dA, aB, bB, dB;

    wload2(p + (size_t)(r0 - 1) * W, lane, r0 > 0, alA, aA, arA, alB, aB, arB);
    wload2(p + (size_t)r0 * W,       lane, true,   blA, bA, brA, blB, bB, brB);

    float s = 0.0f, ss = 0.0f;
    for (int r = r0; r < r0 + 8; ++r) {
        wload2(p + (size_t)(r + 1) * W, lane, (r + 1) < H, dlA, dA, drA, dlB, dB, drB);
        float4 oA = conv_row(alA, aA, arA, blA, bA, brA, dlA, dA, drA);
        float4 oB = conv_row(alB, aB, arB, blB, bB, brB, dlB, dB, drB);
        s  += ((oA.x + oA.y) + (oA.z + oA.w)) + ((oB.x + oB.y) + (oB.z + oB.w));
        ss += ((oA.x*oA.x + oA.y*oA.y) + (oA.z*oA.z + oA.w*oA.w))
            + ((oB.x*oB.x + oB.y*oB.y) + (oB.z*oB.z + oB.w*oB.w));
        alA = blA; aA = bA; arA = brA;  alB = blB; aB = bB; arB = brB;
        blA = dlA; bA = dA; brA = drA;  blB = dlB; bB = dB; brB = drB;
    }

    for (int off = 32; off > 0; off >>= 1) {
        s  += __shfl_down(s,  off);
        ss += __shfl_down(ss, off);
    }
    __shared__ float sh[8];
    if (lane == 0) { sh[wid * 2] = s; sh[wid * 2 + 1] = ss; }
    __syncthreads();
    if (tid == 0) {
        ws[blockIdx.x * 2 + 0] = (sh[0] + sh[2]) + (sh[4] + sh[6]);
        ws[blockIdx.x * 2 + 1] = (sh[1] + sh[3]) + (sh[5] + sh[7]);
    }
}

// Pass 2: reduce the plane's 16 partials, recompute conv (x is L3-resident),
// normalize, nontemporal-store.
__global__ __launch_bounds__(256, 4) void norm_kernel(const float* __restrict__ x,
                                                      const float* __restrict__ ws,
                                                      float* __restrict__ out) {
    const int tid   = threadIdx.x;
    const int wid   = tid >> 6;
    const int lane  = tid & 63;
    const int plane = blockIdx.x >> 4;
    const int slab  = blockIdx.x & 15;
    const int r0    = slab * 32 + wid * 8;
    const int c0A   = lane * 4;
    const int c0B   = 256 + lane * 4;

    const float* __restrict__ p = x + (size_t)plane * H * W;

    // Prefetch the first two rows BEFORE touching the partials: the row loads
    // are independent of the stats, so their L3 latency hides under the
    // partial-read + reduce + syncthreads.
    float alA, arA, blA, brA, dlA, drA;
    float alB, arB, blB, brB, dlB, drB;
    float4 aA, bA, dA, aB, bB, dB;
    wload2(p + (size_t)(r0 - 1) * W, lane, r0 > 0, alA, aA, arA, alB, aB, arB);
    wload2(p + (size_t)r0 * W,       lane, true,   blA, bA, brA, blB, bB, brB);

    // plane stats: 16 (s,ss) pairs; wave 0 reduces, LDS-broadcasts.
    __shared__ float sb[2];
    if (tid < 64) {
        float s = 0.0f, ss = 0.0f;
        if (lane < 16) {
            s  = ws[(plane * 16 + lane) * 2 + 0];
            ss = ws[(plane * 16 + lane) * 2 + 1];
        }
        for (int off = 8; off > 0; off >>= 1) {
            s  += __shfl_down(s,  off);
            ss += __shfl_down(ss, off);
        }
        if (lane == 0) { sb[0] = s; sb[1] = ss; }
    }
    __syncthreads();
    const float invN = 1.0f / (float)(H * W);
    const float mean = sb[0] * invN;
    const float var  = sb[1] * invN - mean * mean;
    const float rstd = rsqrtf(var + 4e-5f);

    float* __restrict__ q = out + (size_t)plane * H * W;

    for (int r = r0; r < r0 + 8; ++r) {
        wload2(p + (size_t)(r + 1) * W, lane, (r + 1) < H, dlA, dA, drA, dlB, dB, drB);
        float4 oA = conv_row(alA, aA, arA, blA, bA, brA, dlA, dA, drA);
        float4 oB = conv_row(alB, aB, arB, blB, bB, brB, dlB, dB, drB);
        vfloat4 yA, yB;
        yA.x = (oA.x - mean) * rstd;
        yA.y = (oA.y - mean) * rstd;
        yA.z = (oA.z - mean) * rstd;
        yA.w = (oA.w - mean) * rstd;
        yB.x = (oB.x - mean) * rstd;
        yB.y = (oB.y - mean) * rstd;
        yB.z = (oB.z - mean) * rstd;
        yB.w = (oB.w - mean) * rstd;
        __builtin_nontemporal_store(yA, reinterpret_cast<vfloat4*>(q + (size_t)r * W + c0A));
        __builtin_nontemporal_store(yB, reinterpret_cast<vfloat4*>(q + (size_t)r * W + c0B));
        alA = blA; aA = bA; arA = brA;  alB = blB; aB = bB; arB = brB;
        blA = dlA; bA = dA; brA = drA;  blB = dlB; bB = dB; brB = drB;
    }
}

extern "C" void kernel_launch(void* const* d_in, const int* in_sizes, int n_in,
                              void* d_out, int out_size, void* d_ws, size_t ws_size,
                              hipStream_t stream) {
    const float* x = (const float*)d_in[0];
    float* out = (float*)d_out;
    float* ws  = (float*)d_ws;

    stats_kernel<<<dim3(NBLOCKS), dim3(256), 0, stream>>>(x, ws);
    norm_kernel <<<dim3(NBLOCKS), dim3(256), 0, stream>>>(x, ws, out);
}

// Round 4
// 250.327 us; speedup vs baseline: 1.8413x; 1.0472x over previous
//
#include <hip/hip_runtime.h>

// Problem: x (32,4,512,512) fp32.
// reference = InstanceNorm( sum_j (2^j/15) * ((x * k_j + 1) * 0.5) )
// Collapses to: c = x * K (single 3x3 depthwise, zero pad, K entries sum to 0,
// center weight 1), then (c - mean_c) * rsqrt(var_c + 4e-5)
//
// Geometry = round-0 best (93 us combined): 2048 blocks x 256 thr (4 waves),
// wave = 16-row x 256-col strip, halos: lane-neighbor shuffles + 2 exec-masked
// scalar loads (L1-hit) at the segment edges.  R3 lesson: wave-wide DS
// shuffles for the seam cost more than 2 masked scalar loads.
// New in R4: depth-2 software pipeline. Row loads are split into
//   wissue  (raw float4 + masked edge scalars, no dependent ops)
//   wextract(shuffle halos at consumption time)
// and row r+2 is issued while row r is convolved, so each VMEM load gets a
// full conv iteration (~50 VALU) of latency cover instead of stalling its
// own iteration.
// R2 lesson kept: NO min-waves launch_bounds arg (it over-squeezes VGPRs and
// spills); natural allocation ~48 VGPR stays <=64 -> 32 waves/CU.

#define H 512
#define W 512
#define PLANES 128
#define NBLOCKS (PLANES * 16)   // 16 blocks/plane, 32 rows x 512 cols per block

typedef float vfloat4 __attribute__((ext_vector_type(4)));

// combined kernel weights (x 1/30): [-8 -4 -2; -1 30 -1; -2 -4 -8]
#define WT0 (-8.0f/30.0f)
#define WT1 (-4.0f/30.0f)
#define WT2 (-2.0f/30.0f)
#define WM  (-1.0f/30.0f)

// Issue the loads for one row segment: coalesced float4 + masked edge
// scalars (lanes 0/63 only; those lines are L1/L2-resident). No shuffles
// here -> nothing forces an early vmcnt wait.
__device__ __forceinline__ void wissue(const float* __restrict__ rowp, int c0, int ch,
                                       int lane, bool valid,
                                       float4& m, float& lv, float& rv) {
    lv = 0.0f; rv = 0.0f;
    if (valid) {
        m = *reinterpret_cast<const float4*>(rowp + c0);
        if (lane == 0  && ch > 0)        lv = rowp[ch - 1];
        if (lane == 63 && ch + 256 < W)  rv = rowp[ch + 256];
    } else {
        m = make_float4(0.0f, 0.0f, 0.0f, 0.0f);
    }
}

// Extract halos at consumption: 2 shuffles, boundary lanes take the scalar.
__device__ __forceinline__ void wextract(const float4& m, float lv, float rv, int lane,
                                         float& l, float& r) {
    float fromL = __shfl_up(m.w, 1);    // lane i <- lane i-1 last elem
    float fromR = __shfl_down(m.x, 1);  // lane i <- lane i+1 first elem
    l = (lane == 0)  ? lv : fromL;
    r = (lane == 63) ? rv : fromR;
}

// 180-degree-symmetric kernel -> pair taps: 4 FMA + 4 ADD per output.
__device__ __forceinline__ float4 conv_row(float al, float4 a, float ar,
                                           float bl, float4 b, float br,
                                           float dl, float4 d, float dr) {
    float4 o;
    o.x = b.x + WT0*(al  + d.y) + WT1*(a.x + d.x) + WT2*(a.y + dl ) + WM*(bl  + b.y);
    o.y = b.y + WT0*(a.x + d.z) + WT1*(a.y + d.y) + WT2*(a.z + d.x) + WM*(b.x + b.z);
    o.z = b.z + WT0*(a.y + d.w) + WT1*(a.z + d.z) + WT2*(a.w + d.y) + WM*(b.y + b.w);
    o.w = b.w + WT0*(a.z + dr ) + WT1*(a.w + d.w) + WT2*(ar  + d.z) + WM*(b.z + br );
    return o;
}

// Pass 1: conv on the fly, per-block (sum, sumsq) partial.
__global__ __launch_bounds__(256) void stats_kernel(const float* __restrict__ x,
                                                    float* __restrict__ ws) {
    const int tid   = threadIdx.x;
    const int wid   = tid >> 6;
    const int lane  = tid & 63;
    const int plane = blockIdx.x >> 4;
    const int slab  = blockIdx.x & 15;          // 32-row slab
    const int ch = (wid & 1) * 256;             // col segment start
    const int c0 = ch + lane * 4;
    const int r0 = slab * 32 + (wid >> 1) * 16; // 16-row strip

    const float* __restrict__ p = x + (size_t)plane * H * W;

    float4 am, bm, cm, nm;
    float alv, arv, blv, brv, clv, crv, nlv, nrv;
    // prologue: rows r0-1, r0, r0+1 in flight (r0+1 <= 497 < H always)
    wissue(p + (size_t)(r0 - 1) * W, c0, ch, lane, r0 > 0, am, alv, arv);
    wissue(p + (size_t)r0 * W,       c0, ch, lane, true,   bm, blv, brv);
    wissue(p + (size_t)(r0 + 1) * W, c0, ch, lane, true,   cm, clv, crv);

    float al, ar, bl, br;
    wextract(am, alv, arv, lane, al, ar);
    wextract(bm, blv, brv, lane, bl, br);

    float s = 0.0f, ss = 0.0f;
    for (int r = r0; r < r0 + 16; ++r) {
        // issue row r+2 (consumed next iteration); last useful row is r0+16
        const bool nvalid = (r + 2 < H) && (r + 2 <= r0 + 16);
        wissue(p + (size_t)(r + 2) * W, c0, ch, lane, nvalid, nm, nlv, nrv);
        float cl, cr;
        wextract(cm, clv, crv, lane, cl, cr);
        float4 o = conv_row(al, am, ar, bl, bm, br, cl, cm, cr);
        s  += (o.x + o.y) + (o.z + o.w);
        ss += (o.x*o.x + o.y*o.y) + (o.z*o.z + o.w*o.w);
        am = bm; al = bl; ar = br;
        bm = cm; bl = cl; br = cr;
        cm = nm; clv = nlv; crv = nrv;
    }

    for (int off = 32; off > 0; off >>= 1) {
        s  += __shfl_down(s,  off);
        ss += __shfl_down(ss, off);
    }
    __shared__ float sh[8];
    if (lane == 0) { sh[wid * 2] = s; sh[wid * 2 + 1] = ss; }
    __syncthreads();
    if (tid == 0) {
        ws[blockIdx.x * 2 + 0] = (sh[0] + sh[2]) + (sh[4] + sh[6]);
        ws[blockIdx.x * 2 + 1] = (sh[1] + sh[3]) + (sh[5] + sh[7]);
    }
}

// Pass 2: reduce the plane's 16 partials, recompute conv (x is L3-resident),
// normalize, nontemporal-store.
__global__ __launch_bounds__(256) void norm_kernel(const float* __restrict__ x,
                                                   const float* __restrict__ ws,
                                                   float* __restrict__ out) {
    const int tid   = threadIdx.x;
    const int wid   = tid >> 6;
    const int lane  = tid & 63;
    const int plane = blockIdx.x >> 4;
    const int slab  = blockIdx.x & 15;
    const int ch = (wid & 1) * 256;
    const int c0 = ch + lane * 4;
    const int r0 = slab * 32 + (wid >> 1) * 16;

    const float* __restrict__ p = x + (size_t)plane * H * W;

    // Prefetch the first three rows BEFORE touching the partials: their L3
    // latency hides under the partial-read + reduce + syncthreads.
    float4 am, bm, cm, nm;
    float alv, arv, blv, brv, clv, crv, nlv, nrv;
    wissue(p + (size_t)(r0 - 1) * W, c0, ch, lane, r0 > 0, am, alv, arv);
    wissue(p + (size_t)r0 * W,       c0, ch, lane, true,   bm, blv, brv);
    wissue(p + (size_t)(r0 + 1) * W, c0, ch, lane, true,   cm, clv, crv);

    // plane stats: 16 (s,ss) pairs; wave 0 reduces, LDS-broadcasts.
    __shared__ float sb[2];
    if (tid < 64) {
        float s = 0.0f, ss = 0.0f;
        if (lane < 16) {
            s  = ws[(plane * 16 + lane) * 2 + 0];
            ss = ws[(plane * 16 + lane) * 2 + 1];
        }
        for (int off = 8; off > 0; off >>= 1) {
            s  += __shfl_down(s,  off);
            ss += __shfl_down(ss, off);
        }
        if (lane == 0) { sb[0] = s; sb[1] = ss; }
    }
    __syncthreads();
    const float invN = 1.0f / (float)(H * W);
    const float mean = sb[0] * invN;
    const float var  = sb[1] * invN - mean * mean;
    const float rstd = rsqrtf(var + 4e-5f);

    float al, ar, bl, br;
    wextract(am, alv, arv, lane, al, ar);
    wextract(bm, blv, brv, lane, bl, br);

    float* __restrict__ q = out + (size_t)plane * H * W;

    for (int r = r0; r < r0 + 16; ++r) {
        const bool nvalid = (r + 2 < H) && (r + 2 <= r0 + 16);
        wissue(p + (size_t)(r + 2) * W, c0, ch, lane, nvalid, nm, nlv, nrv);
        float cl, cr;
        wextract(cm, clv, crv, lane, cl, cr);
        float4 o = conv_row(al, am, ar, bl, bm, br, cl, cm, cr);
        vfloat4 y;
        y.x = (o.x - mean) * rstd;
        y.y = (o.y - mean) * rstd;
        y.z = (o.z - mean) * rstd;
        y.w = (o.w - mean) * rstd;
        __builtin_nontemporal_store(y, reinterpret_cast<vfloat4*>(q + (size_t)r * W + c0));
        am = bm; al = bl; ar = br;
        bm = cm; bl = cl; br = cr;
        cm = nm; clv = nlv; crv = nrv;
    }
}

extern "C" void kernel_launch(void* const* d_in, const int* in_sizes, int n_in,
                              void* d_out, int out_size, void* d_ws, size_t ws_size,
                              hipStream_t stream) {
    const float* x = (const float*)d_in[0];
    float* out = (float*)d_out;
    float* ws  = (float*)d_ws;

    stats_kernel<<<dim3(NBLOCKS), dim3(256), 0, stream>>>(x, ws);
    norm_kernel <<<dim3(NBLOCKS), dim3(256), 0, stream>>>(x, ws, out);
}